// Round 2
// baseline (653.684 us; speedup 1.0000x reference)
//
#include <hip/hip_runtime.h>

// out = zeros(8, 4096, 4096); out[:, u, v] = (edge_attr @ W + b).T, last-write-wins.
#define N_NODES 4096
#define N_EDGES 131072
#define D_EDGE  128
#define N_HEADS 8

// d_ws layout:
//   [0, 4 MiB)        : scores, E*8 f32, [e][h]
//   [4 MiB, 68 MiB)   : winner table, N*N int32 (zeroed each launch)
#define WS_SCORES_OFF  0
#define WS_WINNER_OFF  ((size_t)N_EDGES * N_HEADS * sizeof(float))

// Pass A: dense coalesced score compute + winner atomicMax.
// Winner stored as e+1 (>0) over zeroed table; signed atomicMax = last-write-wins.
__global__ void edgebias_scores_winner(const int* __restrict__ edge_index,
                                       const float* __restrict__ edge_attr,
                                       const float* __restrict__ W,
                                       const float* __restrict__ b,
                                       float* __restrict__ scores,
                                       int* __restrict__ winner) {
    __shared__ float Ws[D_EDGE * N_HEADS];   // 4 KB [d][h]
    __shared__ float bs[N_HEADS];
    for (int i = threadIdx.x; i < D_EDGE * N_HEADS; i += blockDim.x)
        Ws[i] = W[i];
    if (threadIdx.x < N_HEADS) bs[threadIdx.x] = b[threadIdx.x];
    __syncthreads();

    int e = blockIdx.x * blockDim.x + threadIdx.x;
    if (e >= N_EDGES) return;

    float acc[N_HEADS];
    #pragma unroll
    for (int h = 0; h < N_HEADS; ++h) acc[h] = bs[h];

    const float4* row = (const float4*)(edge_attr + (size_t)e * D_EDGE);
    #pragma unroll 8
    for (int j = 0; j < D_EDGE / 4; ++j) {
        float4 a = row[j];
        int d = j * 4;
        #pragma unroll
        for (int h = 0; h < N_HEADS; ++h) {
            acc[h] += a.x * Ws[(d + 0) * N_HEADS + h]
                    + a.y * Ws[(d + 1) * N_HEADS + h]
                    + a.z * Ws[(d + 2) * N_HEADS + h]
                    + a.w * Ws[(d + 3) * N_HEADS + h];
        }
    }

    float4 s0 = make_float4(acc[0], acc[1], acc[2], acc[3]);
    float4 s1 = make_float4(acc[4], acc[5], acc[6], acc[7]);
    ((float4*)scores)[(size_t)e * 2 + 0] = s0;
    ((float4*)scores)[(size_t)e * 2 + 1] = s1;

    int u = edge_index[e];
    int v = edge_index[N_EDGES + e];
    atomicMax(&winner[u * N_NODES + v], e + 1);
}

// Pass B: pure scatter, one thread per (edge, head). 1M threads, 4096 blocks.
// 8 consecutive threads share the same edge -> idx/winner loads coalesce to one
// line; score read is contiguous; one 4B scattered store per thread.
__global__ void edgebias_scatter(const int* __restrict__ edge_index,
                                 const float* __restrict__ scores,
                                 const int* __restrict__ winner,
                                 float* __restrict__ out) {
    int t = blockIdx.x * blockDim.x + threadIdx.x;   // 0 .. E*8-1
    int e = t >> 3;
    int h = t & 7;
    int u = edge_index[e];
    int v = edge_index[N_EDGES + e];
    size_t cell = (size_t)u * N_NODES + v;
    if (winner[cell] == e + 1)
        out[(size_t)h * N_NODES * N_NODES + cell] = scores[t];
}

extern "C" void kernel_launch(void* const* d_in, const int* in_sizes, int n_in,
                              void* d_out, int out_size, void* d_ws, size_t ws_size,
                              hipStream_t stream) {
    const int*   edge_index = (const int*)  d_in[0];  // (2, E) int32
    const float* edge_attr  = (const float*)d_in[1];  // (E, 128) f32
    const float* W          = (const float*)d_in[2];  // (128, 8) f32
    const float* b          = (const float*)d_in[3];  // (8,) f32
    float* out = (float*)d_out;                       // (8, 4096, 4096) f32

    float* scores = (float*)((char*)d_ws + WS_SCORES_OFF);
    int*   winner = (int*)  ((char*)d_ws + WS_WINNER_OFF);

    // Zero output (512 MiB) and winner table (64 MiB).
    hipMemsetAsync(d_out, 0, (size_t)N_HEADS * N_NODES * N_NODES * sizeof(float), stream);
    hipMemsetAsync(winner, 0, (size_t)N_NODES * N_NODES * sizeof(int), stream);

    // Pass A: scores + winner ids.
    edgebias_scores_winner<<<dim3((N_EDGES + 255) / 256), dim3(256), 0, stream>>>(
        edge_index, edge_attr, W, b, scores, winner);

    // Pass B: scatter, one thread per (e, h).
    edgebias_scatter<<<dim3((N_EDGES * N_HEADS) / 256), dim3(256), 0, stream>>>(
        edge_index, scores, winner, out);
}

// Round 3
// 622.924 us; speedup vs baseline: 1.0494x; 1.0494x over previous
//
#include <hip/hip_runtime.h>

// out = zeros(8, 4096, 4096); out[:, u, v] = (edge_attr @ W + b).T, last-write-wins.
#define N_NODES 4096
#define N_EDGES 131072
#define D_EDGE  128
#define N_HEADS 8
#define N_CELLS ((size_t)N_NODES * N_NODES)   // 16,777,216

// d_ws layout:
//   [0, 4 MiB)      : scores, E*8 f32, [e][h]
//   [4 MiB, 68 MiB) : winner table, N*N int32 (zeroed each launch; holds e+1)
#define WS_SCORES_OFF  0
#define WS_WINNER_OFF  ((size_t)N_EDGES * N_HEADS * sizeof(float))

// Pass A: dense coalesced score compute + winner atomicMax.
// Winner stored as e+1 (>0) over zeroed table; signed atomicMax = last-write-wins.
__global__ void edgebias_scores_winner(const int* __restrict__ edge_index,
                                       const float* __restrict__ edge_attr,
                                       const float* __restrict__ W,
                                       const float* __restrict__ b,
                                       float* __restrict__ scores,
                                       int* __restrict__ winner) {
    __shared__ float Ws[D_EDGE * N_HEADS];   // 4 KB [d][h]
    __shared__ float bs[N_HEADS];
    for (int i = threadIdx.x; i < D_EDGE * N_HEADS; i += blockDim.x)
        Ws[i] = W[i];
    if (threadIdx.x < N_HEADS) bs[threadIdx.x] = b[threadIdx.x];
    __syncthreads();

    int e = blockIdx.x * blockDim.x + threadIdx.x;
    if (e >= N_EDGES) return;

    float acc[N_HEADS];
    #pragma unroll
    for (int h = 0; h < N_HEADS; ++h) acc[h] = bs[h];

    const float4* row = (const float4*)(edge_attr + (size_t)e * D_EDGE);
    #pragma unroll 8
    for (int j = 0; j < D_EDGE / 4; ++j) {
        float4 a = row[j];
        int d = j * 4;
        #pragma unroll
        for (int h = 0; h < N_HEADS; ++h) {
            acc[h] += a.x * Ws[(d + 0) * N_HEADS + h]
                    + a.y * Ws[(d + 1) * N_HEADS + h]
                    + a.z * Ws[(d + 2) * N_HEADS + h]
                    + a.w * Ws[(d + 3) * N_HEADS + h];
        }
    }

    ((float4*)scores)[(size_t)e * 2 + 0] = make_float4(acc[0], acc[1], acc[2], acc[3]);
    ((float4*)scores)[(size_t)e * 2 + 1] = make_float4(acc[4], acc[5], acc[6], acc[7]);

    int u = edge_index[e];
    int v = edge_index[N_EDGES + e];
    atomicMax(&winner[u * N_NODES + v], e + 1);
}

// Pass B ("paint"): write the ENTIRE output in streaming order, fusing the
// zero-fill with the scatter. Each thread owns 4 consecutive cells:
//   - one coalesced int4 winner read
//   - rare float4x2 score gathers (0.8% of cells are edges)
//   - 8 coalesced float4 stores (one per head plane)
// All stores are sequential -> no random-store RMW at DRAM.
__global__ void edgebias_paint(const float* __restrict__ scores,
                               const int* __restrict__ winner,
                               float* __restrict__ out) {
    size_t t = (size_t)blockIdx.x * blockDim.x + threadIdx.x;  // 0 .. N_CELLS/4-1
    int4 w = ((const int4*)winner)[t];

    float sc[4][N_HEADS];
    #pragma unroll
    for (int c = 0; c < 4; ++c)
        #pragma unroll
        for (int h = 0; h < N_HEADS; ++h)
            sc[c][h] = 0.0f;

    int we[4] = {w.x, w.y, w.z, w.w};
    #pragma unroll
    for (int c = 0; c < 4; ++c) {
        if (we[c] != 0) {
            const float4* sp = (const float4*)scores + (size_t)(we[c] - 1) * 2;
            float4 lo = sp[0];
            float4 hi = sp[1];
            sc[c][0] = lo.x; sc[c][1] = lo.y; sc[c][2] = lo.z; sc[c][3] = lo.w;
            sc[c][4] = hi.x; sc[c][5] = hi.y; sc[c][6] = hi.z; sc[c][7] = hi.w;
        }
    }

    float4* out4 = (float4*)out;
    #pragma unroll
    for (int h = 0; h < N_HEADS; ++h) {
        out4[(size_t)h * (N_CELLS / 4) + t] =
            make_float4(sc[0][h], sc[1][h], sc[2][h], sc[3][h]);
    }
}

extern "C" void kernel_launch(void* const* d_in, const int* in_sizes, int n_in,
                              void* d_out, int out_size, void* d_ws, size_t ws_size,
                              hipStream_t stream) {
    const int*   edge_index = (const int*)  d_in[0];  // (2, E) int32
    const float* edge_attr  = (const float*)d_in[1];  // (E, 128) f32
    const float* W          = (const float*)d_in[2];  // (128, 8) f32
    const float* b          = (const float*)d_in[3];  // (8,) f32
    float* out = (float*)d_out;                       // (8, 4096, 4096) f32

    float* scores = (float*)((char*)d_ws + WS_SCORES_OFF);
    int*   winner = (int*)  ((char*)d_ws + WS_WINNER_OFF);

    // Zero only the 64 MiB winner table (the output is fully painted in pass B).
    hipMemsetAsync(winner, 0, N_CELLS * sizeof(int), stream);

    // Pass A: scores + winner ids.
    edgebias_scores_winner<<<dim3((N_EDGES + 255) / 256), dim3(256), 0, stream>>>(
        edge_index, edge_attr, W, b, scores, winner);

    // Pass B: paint all 512 MiB of output (zeros + winning scores), coalesced.
    edgebias_paint<<<dim3((unsigned)(N_CELLS / 4 / 256)), dim3(256), 0, stream>>>(
        scores, winner, out);
}